// Round 13
// baseline (180.639 us; speedup 1.0000x reference)
//
#include <hip/hip_runtime.h>
#include <hip/hip_bf16.h>

typedef unsigned short u16;
typedef __attribute__((ext_vector_type(4))) int   int4v;
typedef __attribute__((ext_vector_type(4))) unsigned int uint4v;
typedef __attribute__((ext_vector_type(4))) unsigned short ushort4v;
typedef __attribute__((ext_vector_type(4))) float floatx4;
typedef __attribute__((ext_vector_type(8))) short bf16x8;

#define LRELU_NS 0.01f
#define SK 264   // LDS k-stride (bf16): 256 + 8 pad, 16B-aligned rows

__device__ __forceinline__ float bitsToF(unsigned int b) {
    union { unsigned int u; float f; } v; v.u = b << 16; return v.f;
}
__device__ __forceinline__ float bfLo(unsigned int d) {
    union { unsigned int u; float f; } v; v.u = d << 16; return v.f;
}
__device__ __forceinline__ float bfHi(unsigned int d) {
    union { unsigned int u; float f; } v; v.u = d & 0xffff0000u; return v.f;
}
__device__ __forceinline__ u16 f2bf(float f) {
    __hip_bfloat16 h = __float2bfloat16(f);
    return *reinterpret_cast<u16*>(&h);
}
// exact same values as max(v,0)+0.01*min(v,0), 2 VALU ops
__device__ __forceinline__ float lrelu(float v) {
    return fmaxf(v, LRELU_NS * v);
}
// dtype-adaptive element fetch (isF32 is block-uniform)
__device__ __forceinline__ u16 ldW(const void* p, int i, int isF32) {
    return isF32 ? f2bf(((const float*)p)[i]) : ((const u16*)p)[i];
}
__device__ __forceinline__ float ldF(const void* p, int i, int isF32) {
    return isF32 ? ((const float*)p)[i]
                 : bitsToF((unsigned int)((const u16*)p)[i]);
}

// ---------------------------------------------------------------------------
// Inlined dtype probe (verified R8/R12). Call unconditionally, all threads.
// ---------------------------------------------------------------------------
__device__ __forceinline__ int computeIsF32(const u16* y, int* cnt, int t) {
    if (t == 0) *cnt = 0;
    __syncthreads();
    if (t < 256) {
        u16 v = y[2 * t];
        int e = (v >> 7) & 0xFF;
        if (v == 0 || (e >= 96 && e < 160)) atomicAdd(cnt, 1);
    }
    __syncthreads();
    return (*cnt < 192) ? 1 : 0;
}

// ---------------------------------------------------------------------------
// Kernel 1: pack — UNCHANGED from R12 (verified).
// blocks 0..63: WallT transpose tiles; 64..127: W2T; 128..131: biasF;
// 132..291: Xbf (fp32 world only).
// ---------------------------------------------------------------------------
__global__ __launch_bounds__(256) void pack_kernel(
    const void* __restrict__ yhat,
    const void* __restrict__ Ws1, const void* __restrict__ Wc1,
    const void* __restrict__ Wb1, const void* __restrict__ Ws2,
    const void* __restrict__ Wc2,
    const void* __restrict__ bs1, const void* __restrict__ bc1,
    const void* __restrict__ bb1, const void* __restrict__ bs2,
    const void* __restrict__ bc2, const void* __restrict__ bb2,
    u16* __restrict__ WallT, u16* __restrict__ W2T, float* __restrict__ biasF,
    u16* __restrict__ Xbf)
{
    __shared__ int fcnt;
    const int bid = blockIdx.x, t = threadIdx.x;
    const int isF32 = computeIsF32((const u16*)yhat, &fcnt, t);
    if (bid < 64) {
        __shared__ u16 tile[64][65];
        const int c0 = (bid & 15) * 64;      // col-tile in [0,1024)
        const int k0 = (bid >> 4) * 64;      // k-tile in [0,256)
        const void* src; int coff; int roff = 0;
        if (c0 < 256)      { src = Ws1; coff = c0; }
        else if (c0 < 512) { src = Wc1; coff = c0 - 256; }
        else if (c0 < 768) { src = Wb1; coff = c0 - 512; }
        else               { src = Wb1; coff = c0 - 768; roff = 256; }
        const int cc = t & 63, kk0 = t >> 6;
        #pragma unroll
        for (int i = 0; i < 16; ++i) {
            int kk = kk0 + i * 4;
            tile[kk][cc] = ldW(src, (k0 + kk + roff) * 256 + coff + cc, isF32);
        }
        __syncthreads();
        const int kk2 = t & 63, cc0 = t >> 6;
        #pragma unroll
        for (int i = 0; i < 16; ++i) {
            int cc2 = cc0 + i * 4;
            WallT[(c0 + cc2) * 256 + (k0 + kk2)] = tile[kk2][cc2];
        }
    } else if (bid < 128) {
        int e2 = (bid - 64) * 256 + t;       // < 16384
        int c = e2 >> 8, k = e2 & 255;
        u16 v = 0;
        if (c < 40)                 v = ldW(Ws2, k * 40 + c, isF32);
        else if (c >= 48 && c < 53) v = ldW(Wc2, k * 5 + (c - 48), isF32);
        W2T[c * 256 + k] = v;
    } else if (bid < 132) {
        int idx = (bid - 128) * 256 + t;     // < 1024
        float v = 0.f;
        if (idx < 256)       v = ldF(bs1, idx, isF32);
        else if (idx < 512)  v = ldF(bc1, idx - 256, isF32);
        else if (idx < 768)  v = ldF(bb1, idx - 512, isF32);
        else if (idx < 808)  v = ldF(bs2, idx - 768, isF32);
        else if (idx < 813)  v = ldF(bc2, idx - 808, isF32);
        else if (idx >= 816 && idx < 821) v = ldF(bb2, idx - 816, isF32);
        biasF[idx] = v;
    } else {
        // Xbf conversion: 160 blocks x 16384 elements; only in fp32 world
        if (!isF32) return;
        const floatx4* __restrict__ xf = (const floatx4*)yhat;
        const int base4 = (bid - 132) * 4096;       // float4-chunk base
        #pragma unroll
        for (int it = 0; it < 16; ++it) {
            int c4 = base4 + t + it * 256;
            floatx4 f = xf[c4];
            ushort4v u;
            u[0] = f2bf(f[0]); u[1] = f2bf(f[1]); u[2] = f2bf(f[2]); u[3] = f2bf(f[3]);
            *(ushort4v*)&Xbf[c4 * 4] = u;
        }
    }
}

// ---------------------------------------------------------------------------
// Kernel 2: symbols + charges — UNCHANGED from R12 (verified).
// ---------------------------------------------------------------------------
__global__ __launch_bounds__(256, 4) void heads_kernel(
    const void* __restrict__ Xv, const u16* __restrict__ Xbf,
    const u16* __restrict__ WallT,
    const u16* __restrict__ W2T, const float* __restrict__ biasF,
    void* __restrict__ outv)
{
    __shared__ u16 Hb[64 * SK];
    __shared__ int fcnt;
    const int t = threadIdx.x;
    const int bm0 = blockIdx.x * 64;
    const int head = blockIdx.y;
    const int isF32 = computeIsF32((const u16*)Xv, &fcnt, t);
    const u16* __restrict__ Xb = isF32 ? Xbf : (const u16*)Xv;

    const int w = t >> 6, l = t & 63;
    const int ml = l & 15, kq = l >> 4, r0 = kq * 4;

    // hoist A-frags for M-tile mt = w: row bm0 + w*16 + ml
    bf16x8 a8[8];
    {
        const u16* __restrict__ ap = Xb + (bm0 + w * 16 + ml) * 256 + kq * 8;
        #pragma unroll
        for (int ks = 0; ks < 8; ++ks)
            a8[ks] = *(const bf16x8*)(ap + ks * 32);
    }

    // ---- layer 1: all 16 col-tiles, wave-local Hb rows ----
    for (int ct = 0; ct < 16; ++ct) {
        floatx4 acc = {};
        #pragma unroll
        for (int ks = 0; ks < 8; ++ks) {
            const int k0 = ks * 32 + kq * 8;
            bf16x8 bf = *(const bf16x8*)&WallT[(head * 256 + ct * 16 + ml) * 256 + k0];
            acc = __builtin_amdgcn_mfma_f32_16x16x32_bf16(a8[ks], bf, acc, 0, 0, 0);
        }
        const int col = ct * 16 + ml;          // [0,256)
        const float bias = biasF[head * 256 + col];   // bs1 | bc1
        #pragma unroll
        for (int r = 0; r < 4; ++r)
            Hb[(w * 16 + r0 + r) * SK + col] = f2bf(lrelu(acc[r] + bias));
    }
    // no barrier: layer 2 reads only rows w*16.. written by this wave

    // ---- layer 2: wave w owns M-tile w ----
    const int nct = (head == 0) ? 3 : 1;       // block-uniform
    const int c0  = (head == 0) ? 0 : 48;
    floatx4 acc2[3] = {};
    #pragma unroll
    for (int ks = 0; ks < 8; ++ks) {
        const int k0 = ks * 32 + kq * 8;
        bf16x8 a = *(const bf16x8*)&Hb[(w * 16 + ml) * SK + k0];
        #pragma unroll
        for (int j = 0; j < 3; ++j) {
            if (j < nct) {
                bf16x8 bf = *(const bf16x8*)&W2T[(c0 + j * 16 + ml) * 256 + k0];
                acc2[j] = __builtin_amdgcn_mfma_f32_16x16x32_bf16(a, bf, acc2[j], 0, 0, 0);
            }
        }
    }
    #pragma unroll
    for (int j = 0; j < 3; ++j) {
        if (j < nct) {
            const int col = j * 16 + ml;
            const int lim = (head == 0) ? 40 : 5;
            if (col < lim) {
                const float bias = biasF[(head == 0 ? 768 : 808) + col];
                #pragma unroll
                for (int r = 0; r < 4; ++r) {
                    const int row = bm0 + w * 16 + r0 + r;
                    const int o = (head == 0) ? row * 40 + col
                                              : 409600 + row * 5 + col;
                    const float v = acc2[j][r] + bias;
                    if (isF32) ((float*)outv)[o] = v;
                    else ((__hip_bfloat16*)outv)[o] = __float2bfloat16(v);
                }
            }
        }
    }
}

// ---------------------------------------------------------------------------
// Kernel 3: bonds — ONE delta from R12: 1024 threads (16 waves -> 4/SIMD).
// Same LDS, same math, same D-mapping; only ownership strides change:
// layer 1 ct = w+16n (n<2); pair i = w+16m (m<3, i<40); strides 512->1024.
// LDS: P1L 25344 + P2L 25344 + WsB 8448 + fb 16000 = 75136 B.
// ---------------------------------------------------------------------------
__global__ __launch_bounds__(1024, 4) void bonds_kernel(
    const void* __restrict__ Xv, const u16* __restrict__ Xbf,
    const u16* __restrict__ WallT,
    const void* __restrict__ Wb2, const float* __restrict__ biasF,
    void* __restrict__ outv)
{
    __shared__ u16 P1L[48 * SK];
    __shared__ u16 P2L[48 * SK];
    __shared__ u16 WsB[16 * 264];
    __shared__ u16 fb[8000];
    __shared__ int fcnt;
    const int t = threadIdx.x, b = blockIdx.x;
    const int isF32 = computeIsF32((const u16*)Xv, &fcnt, t);
    const u16* __restrict__ Xb = isF32 ? Xbf : (const u16*)Xv;

    // Wb2[256][5] -> WsB[c][k] bf16, c<16 (rows 5..15 zero)
    #pragma unroll
    for (int it = 0; it < 4; ++it) {
        int e2 = t + it * 1024;                // < 4096
        int c = e2 >> 8, k = e2 & 255;
        WsB[c * 264 + k] = (c < 5) ? ldW(Wb2, k * 5 + c, isF32) : (u16)0;
    }

    const int w = t >> 6, l = t & 63;          // w in [0,16)
    const int ml = l & 15, kq = l >> 4, r0 = kq * 4;

    // ---- layer 1: P = X @ Wb1 (+bb1 on P1 half), A and B frags from global ----
    // A rows: molecule-local mt*16+ml, clamped to 39 (rows 40..47 discarded later)
    const u16* __restrict__ xrow[3];
    #pragma unroll
    for (int mt = 0; mt < 3; ++mt) {
        int rr = mt * 16 + ml; if (rr > 39) rr = 39;
        xrow[mt] = Xb + (b * 40 + rr) * 256 + kq * 8;
    }
    #pragma unroll
    for (int n = 0; n < 2; ++n) {
        const int gc = (w + 16 * n) * 16 + ml; // [0,512), unique per (w,n,ml)
        floatx4 acc[3] = {};
        #pragma unroll
        for (int ks = 0; ks < 8; ++ks) {
            const int k0 = ks * 32;
            bf16x8 bf = *(const bf16x8*)&WallT[(512 + gc) * 256 + kq * 8 + k0];
            #pragma unroll
            for (int i = 0; i < 3; ++i) {
                bf16x8 a = *(const bf16x8*)(xrow[i] + k0);
                acc[i] = __builtin_amdgcn_mfma_f32_16x16x32_bf16(a, bf, acc[i], 0, 0, 0);
            }
        }
        u16* dst = (gc < 256) ? P1L : P2L;
        const int col = gc & 255;
        const float bias = (gc < 256) ? biasF[512 + gc] : 0.f;   // bb1 on P1
        #pragma unroll
        for (int i = 0; i < 3; ++i)
            #pragma unroll
            for (int r = 0; r < 4; ++r)
                dst[(i * 16 + r0 + r) * SK + col] = f2bf(acc[i][r] + bias);
    }
    __syncthreads();   // P1L/P2L + WsB visible to all waves

    // ---- pair phase: wave w owns i = w + 16m (i<40); 3 j-tiles per i ----
    bf16x8 wf[8];
    #pragma unroll
    for (int ks = 0; ks < 8; ++ks)
        wf[ks] = *(const bf16x8*)&WsB[ml * 264 + ks * 32 + kq * 8];

    for (int m = 0; m < 3; ++m) {
        const int i = w + 16 * m;              // [0,40) unique; w>=8 skip m=2
        if (i >= 40) break;
        uint4v pa8[8];
        #pragma unroll
        for (int ks = 0; ks < 8; ++ks)
            pa8[ks] = *(const uint4v*)&P1L[i * SK + ks * 32 + kq * 8];
        for (int jt = 0; jt < 3; ++jt) {
            floatx4 acc = {};
            #pragma unroll
            for (int ks = 0; ks < 8; ++ks) {
                const int k0 = ks * 32 + kq * 8;
                uint4v pa = pa8[ks];
                uint4v pb = *(const uint4v*)&P2L[(jt * 16 + ml) * SK + k0];
                int4v ai;
                #pragma unroll
                for (int d = 0; d < 4; ++d) {
                    float lo = lrelu(bfLo(pa[d]) + bfLo(pb[d]));
                    float hi = lrelu(bfHi(pa[d]) + bfHi(pb[d]));
                    unsigned int pl = (unsigned int)f2bf(lo);
                    unsigned int ph = (unsigned int)f2bf(hi);
                    ai[d] = (int)(pl | (ph << 16));
                }
                bf16x8 af = __builtin_bit_cast(bf16x8, ai);
                acc = __builtin_amdgcn_mfma_f32_16x16x32_bf16(af, wf[ks], acc, 0, 0, 0);
            }
            if (ml < 5) {                      // D: row=kq*4+r (j'), col=ml (class)
                #pragma unroll
                for (int r = 0; r < 4; ++r) {
                    const int j = jt * 16 + r0 + r;
                    if (j < 40) fb[(i * 40 + j) * 5 + ml] = f2bf(acc[r]);
                }
            }
        }
    }
    __syncthreads();

    // ---- phase 2: symmetrize + 2*bb2 + store ----
    const int base = 460800 + b * 8000;
    for (int e = t; e < 8000; e += 1024) {
        int pr = e / 5, c = e - pr * 5;
        int i = pr / 40, j = pr - (pr / 40) * 40;
        float v = bitsToF((unsigned int)fb[e])
                + bitsToF((unsigned int)fb[(j * 40 + i) * 5 + c])
                + 2.f * biasF[816 + c];
        if (isF32) ((float*)outv)[base + e] = v;
        else ((__hip_bfloat16*)outv)[base + e] = __float2bfloat16(v);
    }
}

// ---------------------------------------------------------------------------
extern "C" void kernel_launch(void* const* d_in, const int* in_sizes, int n_in,
                              void* d_out, int out_size, void* d_ws, size_t ws_size,
                              hipStream_t stream)
{
    const void* yhat = d_in[0];
    const void* Ws1  = d_in[1];
    const void* bs1  = d_in[2];
    const void* Ws2  = d_in[3];
    const void* bs2  = d_in[4];
    const void* Wc1  = d_in[5];
    const void* bc1  = d_in[6];
    const void* Wc2  = d_in[7];
    const void* bc2  = d_in[8];
    const void* Wb1  = d_in[9];
    const void* bb1  = d_in[10];
    const void* Wb2  = d_in[11];
    const void* bb2  = d_in[12];

    // workspace layout (5,808,128 bytes used)
    char* wsb = (char*)d_ws;
    float* biasF = (float*)(wsb + 4096);     // 1024 floats
    u16*   W2T   = (u16*)(wsb + 8192);       // 64*256 bf16  = 32768 B
    u16*   WallT = (u16*)(wsb + 40960);      // 1024*256 bf16 = 524288 B
    u16*   Xbf   = (u16*)(wsb + 565248);     // 10240*256 bf16 = 5242880 B

    pack_kernel<<<292, 256, 0, stream>>>(yhat, Ws1, Wc1, Wb1, Ws2, Wc2,
                                         bs1, bc1, bb1, bs2, bc2, bb2,
                                         WallT, W2T, biasF, Xbf);
    heads_kernel<<<dim3(160, 2), 256, 0, stream>>>(yhat, Xbf, WallT, W2T, biasF, d_out);
    bonds_kernel<<<256, 1024, 0, stream>>>(yhat, Xbf, WallT, Wb2, biasF, d_out);
}

// Round 14
// 168.155 us; speedup vs baseline: 1.0742x; 1.0742x over previous
//
#include <hip/hip_runtime.h>
#include <hip/hip_bf16.h>

typedef unsigned short u16;
typedef __attribute__((ext_vector_type(4))) int   int4v;
typedef __attribute__((ext_vector_type(4))) unsigned int uint4v;
typedef __attribute__((ext_vector_type(4))) unsigned short ushort4v;
typedef __attribute__((ext_vector_type(4))) float floatx4;
typedef __attribute__((ext_vector_type(8))) short bf16x8;

#define LRELU_NS 0.01f
#define SK 264   // bf16 LDS k-stride
#define PF 268   // fp32 LDS row stride (268%32=12 -> 2-way bank aliasing, free)

__device__ __forceinline__ float bitsToF(unsigned int b) {
    union { unsigned int u; float f; } v; v.u = b << 16; return v.f;
}
__device__ __forceinline__ u16 f2bf(float f) {
    __hip_bfloat16 h = __float2bfloat16(f);
    return *reinterpret_cast<u16*>(&h);
}
// exact same values as max(v,0)+0.01*min(v,0), 2 VALU ops
__device__ __forceinline__ float lrelu(float v) {
    return fmaxf(v, LRELU_NS * v);
}
// dtype-adaptive element fetch (isF32 is block-uniform)
__device__ __forceinline__ u16 ldW(const void* p, int i, int isF32) {
    return isF32 ? f2bf(((const float*)p)[i]) : ((const u16*)p)[i];
}
__device__ __forceinline__ float ldF(const void* p, int i, int isF32) {
    return isF32 ? ((const float*)p)[i]
                 : bitsToF((unsigned int)((const u16*)p)[i]);
}

// ---------------------------------------------------------------------------
// Inlined dtype probe (verified R8/R12). Call unconditionally, all threads.
// ---------------------------------------------------------------------------
__device__ __forceinline__ int computeIsF32(const u16* y, int* cnt, int t) {
    if (t == 0) *cnt = 0;
    __syncthreads();
    if (t < 256) {
        u16 v = y[2 * t];
        int e = (v >> 7) & 0xFF;
        if (v == 0 || (e >= 96 && e < 160)) atomicAdd(cnt, 1);
    }
    __syncthreads();
    return (*cnt < 192) ? 1 : 0;
}

// ---------------------------------------------------------------------------
// Kernel 1: pack — UNCHANGED from R12 (verified).
// ---------------------------------------------------------------------------
__global__ __launch_bounds__(256) void pack_kernel(
    const void* __restrict__ yhat,
    const void* __restrict__ Ws1, const void* __restrict__ Wc1,
    const void* __restrict__ Wb1, const void* __restrict__ Ws2,
    const void* __restrict__ Wc2,
    const void* __restrict__ bs1, const void* __restrict__ bc1,
    const void* __restrict__ bb1, const void* __restrict__ bs2,
    const void* __restrict__ bc2, const void* __restrict__ bb2,
    u16* __restrict__ WallT, u16* __restrict__ W2T, float* __restrict__ biasF,
    u16* __restrict__ Xbf)
{
    __shared__ int fcnt;
    const int bid = blockIdx.x, t = threadIdx.x;
    const int isF32 = computeIsF32((const u16*)yhat, &fcnt, t);
    if (bid < 64) {
        __shared__ u16 tile[64][65];
        const int c0 = (bid & 15) * 64;
        const int k0 = (bid >> 4) * 64;
        const void* src; int coff; int roff = 0;
        if (c0 < 256)      { src = Ws1; coff = c0; }
        else if (c0 < 512) { src = Wc1; coff = c0 - 256; }
        else if (c0 < 768) { src = Wb1; coff = c0 - 512; }
        else               { src = Wb1; coff = c0 - 768; roff = 256; }
        const int cc = t & 63, kk0 = t >> 6;
        #pragma unroll
        for (int i = 0; i < 16; ++i) {
            int kk = kk0 + i * 4;
            tile[kk][cc] = ldW(src, (k0 + kk + roff) * 256 + coff + cc, isF32);
        }
        __syncthreads();
        const int kk2 = t & 63, cc0 = t >> 6;
        #pragma unroll
        for (int i = 0; i < 16; ++i) {
            int cc2 = cc0 + i * 4;
            WallT[(c0 + cc2) * 256 + (k0 + kk2)] = tile[kk2][cc2];
        }
    } else if (bid < 128) {
        int e2 = (bid - 64) * 256 + t;
        int c = e2 >> 8, k = e2 & 255;
        u16 v = 0;
        if (c < 40)                 v = ldW(Ws2, k * 40 + c, isF32);
        else if (c >= 48 && c < 53) v = ldW(Wc2, k * 5 + (c - 48), isF32);
        W2T[c * 256 + k] = v;
    } else if (bid < 132) {
        int idx = (bid - 128) * 256 + t;
        float v = 0.f;
        if (idx < 256)       v = ldF(bs1, idx, isF32);
        else if (idx < 512)  v = ldF(bc1, idx - 256, isF32);
        else if (idx < 768)  v = ldF(bb1, idx - 512, isF32);
        else if (idx < 808)  v = ldF(bs2, idx - 768, isF32);
        else if (idx < 813)  v = ldF(bc2, idx - 808, isF32);
        else if (idx >= 816 && idx < 821) v = ldF(bb2, idx - 816, isF32);
        biasF[idx] = v;
    } else {
        if (!isF32) return;
        const floatx4* __restrict__ xf = (const floatx4*)yhat;
        const int base4 = (bid - 132) * 4096;
        #pragma unroll
        for (int it = 0; it < 16; ++it) {
            int c4 = base4 + t + it * 256;
            floatx4 f = xf[c4];
            ushort4v u;
            u[0] = f2bf(f[0]); u[1] = f2bf(f[1]); u[2] = f2bf(f[2]); u[3] = f2bf(f[3]);
            *(ushort4v*)&Xbf[c4 * 4] = u;
        }
    }
}

// ---------------------------------------------------------------------------
// Kernel 2: symbols + charges — UNCHANGED from R12 (verified).
// ---------------------------------------------------------------------------
__global__ __launch_bounds__(256, 4) void heads_kernel(
    const void* __restrict__ Xv, const u16* __restrict__ Xbf,
    const u16* __restrict__ WallT,
    const u16* __restrict__ W2T, const float* __restrict__ biasF,
    void* __restrict__ outv)
{
    __shared__ u16 Hb[64 * SK];
    __shared__ int fcnt;
    const int t = threadIdx.x;
    const int bm0 = blockIdx.x * 64;
    const int head = blockIdx.y;
    const int isF32 = computeIsF32((const u16*)Xv, &fcnt, t);
    const u16* __restrict__ Xb = isF32 ? Xbf : (const u16*)Xv;

    const int w = t >> 6, l = t & 63;
    const int ml = l & 15, kq = l >> 4, r0 = kq * 4;

    bf16x8 a8[8];
    {
        const u16* __restrict__ ap = Xb + (bm0 + w * 16 + ml) * 256 + kq * 8;
        #pragma unroll
        for (int ks = 0; ks < 8; ++ks)
            a8[ks] = *(const bf16x8*)(ap + ks * 32);
    }

    for (int ct = 0; ct < 16; ++ct) {
        floatx4 acc = {};
        #pragma unroll
        for (int ks = 0; ks < 8; ++ks) {
            const int k0 = ks * 32 + kq * 8;
            bf16x8 bf = *(const bf16x8*)&WallT[(head * 256 + ct * 16 + ml) * 256 + k0];
            acc = __builtin_amdgcn_mfma_f32_16x16x32_bf16(a8[ks], bf, acc, 0, 0, 0);
        }
        const int col = ct * 16 + ml;
        const float bias = biasF[head * 256 + col];
        #pragma unroll
        for (int r = 0; r < 4; ++r)
            Hb[(w * 16 + r0 + r) * SK + col] = f2bf(lrelu(acc[r] + bias));
    }
    // no barrier: layer 2 reads only rows written by this wave

    const int nct = (head == 0) ? 3 : 1;
    const int c0  = (head == 0) ? 0 : 48;
    floatx4 acc2[3] = {};
    #pragma unroll
    for (int ks = 0; ks < 8; ++ks) {
        const int k0 = ks * 32 + kq * 8;
        bf16x8 a = *(const bf16x8*)&Hb[(w * 16 + ml) * SK + k0];
        #pragma unroll
        for (int j = 0; j < 3; ++j) {
            if (j < nct) {
                bf16x8 bf = *(const bf16x8*)&W2T[(c0 + j * 16 + ml) * 256 + k0];
                acc2[j] = __builtin_amdgcn_mfma_f32_16x16x32_bf16(a, bf, acc2[j], 0, 0, 0);
            }
        }
    }
    #pragma unroll
    for (int j = 0; j < 3; ++j) {
        if (j < nct) {
            const int col = j * 16 + ml;
            const int lim = (head == 0) ? 40 : 5;
            if (col < lim) {
                const float bias = biasF[(head == 0 ? 768 : 808) + col];
                #pragma unroll
                for (int r = 0; r < 4; ++r) {
                    const int row = bm0 + w * 16 + r0 + r;
                    const int o = (head == 0) ? row * 40 + col
                                              : 409600 + row * 5 + col;
                    const float v = acc2[j][r] + bias;
                    if (isF32) ((float*)outv)[o] = v;
                    else ((__hip_bfloat16*)outv)[o] = __float2bfloat16(v);
                }
            }
        }
    }
}

// ---------------------------------------------------------------------------
// Kernel 3: bonds — R14 delta (op-count diet, from R13's falsified occupancy
// theory): (1) P1F/P2F fp32 in LDS (no bf16 extracts in pair phase);
// (2) pair-phase processes i-pairs (ia, ia+8) sharing each pb load, pa floats
// hoisted in registers; (3) back to 512 thr / 8 waves (balanced 5 i/wave).
// LDS: P1F 51456 + P2F 51456 + WsB 8448 + fb 16000 = 127360 B. (512,2): no spill.
// ---------------------------------------------------------------------------
__global__ __launch_bounds__(512, 2) void bonds_kernel(
    const void* __restrict__ Xv, const u16* __restrict__ Xbf,
    const u16* __restrict__ WallT,
    const void* __restrict__ Wb2, const float* __restrict__ biasF,
    void* __restrict__ outv)
{
    __shared__ float P1F[48 * PF];
    __shared__ float P2F[48 * PF];
    __shared__ u16 WsB[16 * 264];
    __shared__ u16 fb[8000];
    __shared__ int fcnt;
    const int t = threadIdx.x, b = blockIdx.x;
    const int isF32 = computeIsF32((const u16*)Xv, &fcnt, t);
    const u16* __restrict__ Xb = isF32 ? Xbf : (const u16*)Xv;

    // Wb2[256][5] -> WsB[c][k] bf16, c<16 (rows 5..15 zero)
    #pragma unroll
    for (int it = 0; it < 8; ++it) {
        int e2 = t + it * 512;                 // < 4096
        int c = e2 >> 8, k = e2 & 255;
        WsB[c * 264 + k] = (c < 5) ? ldW(Wb2, k * 5 + c, isF32) : (u16)0;
    }

    const int w = t >> 6, l = t & 63;          // w in [0,8)
    const int ml = l & 15, kq = l >> 4, r0 = kq * 4;

    // ---- layer 1: P = X @ Wb1 (+bb1 on P1 half); store fp32 ----
    const u16* __restrict__ xrow[3];
    #pragma unroll
    for (int mt = 0; mt < 3; ++mt) {
        int rr = mt * 16 + ml; if (rr > 39) rr = 39;
        xrow[mt] = Xb + (b * 40 + rr) * 256 + kq * 8;
    }
    for (int n = 0; n < 4; ++n) {
        const int gc = (w + 8 * n) * 16 + ml;  // [0,512)
        floatx4 acc[3] = {};
        #pragma unroll
        for (int ks = 0; ks < 8; ++ks) {
            const int k0 = ks * 32;
            bf16x8 bf = *(const bf16x8*)&WallT[(512 + gc) * 256 + kq * 8 + k0];
            #pragma unroll
            for (int i = 0; i < 3; ++i) {
                bf16x8 a = *(const bf16x8*)(xrow[i] + k0);
                acc[i] = __builtin_amdgcn_mfma_f32_16x16x32_bf16(a, bf, acc[i], 0, 0, 0);
            }
        }
        float* dst = (gc < 256) ? P1F : P2F;
        const int col = gc & 255;
        const float bias = (gc < 256) ? biasF[512 + gc] : 0.f;   // bb1 on P1
        #pragma unroll
        for (int i = 0; i < 3; ++i)
            #pragma unroll
            for (int r = 0; r < 4; ++r)
                dst[(i * 16 + r0 + r) * PF + col] = acc[i][r] + bias;
    }
    __syncthreads();   // P1F/P2F + WsB visible to all waves

    // ---- pair phase: wave w owns i in {w, w+8, w+16, w+24, w+32}; process
    // pairs (ia, ia+8) for g=0,1 and singleton ia=w+32 for g=2 ----
    bf16x8 wf[8];
    #pragma unroll
    for (int ks = 0; ks < 8; ++ks)
        wf[ks] = *(const bf16x8*)&WsB[ml * 264 + ks * 32 + kq * 8];

    #pragma unroll
    for (int g = 0; g < 3; ++g) {
        const int ia = w + 16 * g;             // < 40 always (w<8)
        const int ib = ia + 8;                 // invalid when g==2
        const bool two = (g < 2);

        floatx4 paA[16], paB[16];              // pa floats, 64(+64) VGPRs
        #pragma unroll
        for (int ks = 0; ks < 8; ++ks) {
            const int k0 = ks * 32 + kq * 8;
            paA[2 * ks]     = *(const floatx4*)&P1F[ia * PF + k0];
            paA[2 * ks + 1] = *(const floatx4*)&P1F[ia * PF + k0 + 4];
            if (two) {
                paB[2 * ks]     = *(const floatx4*)&P1F[ib * PF + k0];
                paB[2 * ks + 1] = *(const floatx4*)&P1F[ib * PF + k0 + 4];
            }
        }
        for (int jt = 0; jt < 3; ++jt) {
            floatx4 accA = {}, accB = {};
            #pragma unroll
            for (int ks = 0; ks < 8; ++ks) {
                const int k0 = ks * 32 + kq * 8;
                floatx4 pb0 = *(const floatx4*)&P2F[(jt * 16 + ml) * PF + k0];
                floatx4 pb1 = *(const floatx4*)&P2F[(jt * 16 + ml) * PF + k0 + 4];
                int4v aiA;
                #pragma unroll
                for (int p = 0; p < 2; ++p) {
                    floatx4 pbp = p ? pb1 : pb0;
                    floatx4 pap = paA[2 * ks + p];
                    #pragma unroll
                    for (int d2 = 0; d2 < 2; ++d2) {
                        float lo = lrelu(pap[2 * d2]     + pbp[2 * d2]);
                        float hi = lrelu(pap[2 * d2 + 1] + pbp[2 * d2 + 1]);
                        aiA[p * 2 + d2] = (int)((unsigned int)f2bf(lo)
                                       | ((unsigned int)f2bf(hi) << 16));
                    }
                }
                accA = __builtin_amdgcn_mfma_f32_16x16x32_bf16(
                    __builtin_bit_cast(bf16x8, aiA), wf[ks], accA, 0, 0, 0);
                if (two) {
                    int4v aiB;
                    #pragma unroll
                    for (int p = 0; p < 2; ++p) {
                        floatx4 pbp = p ? pb1 : pb0;
                        floatx4 pap = paB[2 * ks + p];
                        #pragma unroll
                        for (int d2 = 0; d2 < 2; ++d2) {
                            float lo = lrelu(pap[2 * d2]     + pbp[2 * d2]);
                            float hi = lrelu(pap[2 * d2 + 1] + pbp[2 * d2 + 1]);
                            aiB[p * 2 + d2] = (int)((unsigned int)f2bf(lo)
                                           | ((unsigned int)f2bf(hi) << 16));
                        }
                    }
                    accB = __builtin_amdgcn_mfma_f32_16x16x32_bf16(
                        __builtin_bit_cast(bf16x8, aiB), wf[ks], accB, 0, 0, 0);
                }
            }
            if (ml < 5) {                      // D: row=kq*4+r (j'), col=ml
                #pragma unroll
                for (int r = 0; r < 4; ++r) {
                    const int j = jt * 16 + r0 + r;
                    if (j < 40) {
                        fb[(ia * 40 + j) * 5 + ml] = f2bf(accA[r]);
                        if (two) fb[(ib * 40 + j) * 5 + ml] = f2bf(accB[r]);
                    }
                }
            }
        }
    }
    __syncthreads();

    // ---- phase 2: symmetrize + 2*bb2 + store ----
    const int base = 460800 + b * 8000;
    for (int e = t; e < 8000; e += 512) {
        int pr = e / 5, c = e - pr * 5;
        int i = pr / 40, j = pr - (pr / 40) * 40;
        float v = bitsToF((unsigned int)fb[e])
                + bitsToF((unsigned int)fb[(j * 40 + i) * 5 + c])
                + 2.f * biasF[816 + c];
        if (isF32) ((float*)outv)[base + e] = v;
        else ((__hip_bfloat16*)outv)[base + e] = __float2bfloat16(v);
    }
}

// ---------------------------------------------------------------------------
extern "C" void kernel_launch(void* const* d_in, const int* in_sizes, int n_in,
                              void* d_out, int out_size, void* d_ws, size_t ws_size,
                              hipStream_t stream)
{
    const void* yhat = d_in[0];
    const void* Ws1  = d_in[1];
    const void* bs1  = d_in[2];
    const void* Ws2  = d_in[3];
    const void* bs2  = d_in[4];
    const void* Wc1  = d_in[5];
    const void* bc1  = d_in[6];
    const void* Wc2  = d_in[7];
    const void* bc2  = d_in[8];
    const void* Wb1  = d_in[9];
    const void* bb1  = d_in[10];
    const void* Wb2  = d_in[11];
    const void* bb2  = d_in[12];

    // workspace layout (5,808,128 bytes used)
    char* wsb = (char*)d_ws;
    float* biasF = (float*)(wsb + 4096);     // 1024 floats
    u16*   W2T   = (u16*)(wsb + 8192);       // 64*256 bf16  = 32768 B
    u16*   WallT = (u16*)(wsb + 40960);      // 1024*256 bf16 = 524288 B
    u16*   Xbf   = (u16*)(wsb + 565248);     // 10240*256 bf16 = 5242880 B

    pack_kernel<<<292, 256, 0, stream>>>(yhat, Ws1, Wc1, Wb1, Ws2, Wc2,
                                         bs1, bc1, bb1, bs2, bc2, bb2,
                                         WallT, W2T, biasF, Xbf);
    heads_kernel<<<dim3(160, 2), 256, 0, stream>>>(yhat, Xbf, WallT, W2T, biasF, d_out);
    bonds_kernel<<<256, 512, 0, stream>>>(yhat, Xbf, WallT, Wb2, biasF, d_out);
}

// Round 16
// 164.366 us; speedup vs baseline: 1.0990x; 1.0231x over previous
//
#include <hip/hip_runtime.h>
#include <hip/hip_bf16.h>

typedef unsigned short u16;
typedef __attribute__((ext_vector_type(4))) int   int4v;
typedef __attribute__((ext_vector_type(4))) unsigned int uint4v;
typedef __attribute__((ext_vector_type(4))) unsigned short ushort4v;
typedef __attribute__((ext_vector_type(4))) float floatx4;
typedef __attribute__((ext_vector_type(8))) short bf16x8;

#define LRELU_NS 0.01f
#define SK 264   // bf16 LDS k-stride
#define PF 268   // fp32 LDS row stride (268%32=12 -> 2-way bank aliasing, free)

__device__ __forceinline__ float bitsToF(unsigned int b) {
    union { unsigned int u; float f; } v; v.u = b << 16; return v.f;
}
__device__ __forceinline__ u16 f2bf(float f) {
    __hip_bfloat16 h = __float2bfloat16(f);
    return *reinterpret_cast<u16*>(&h);
}
// exact same values as max(v,0)+0.01*min(v,0), 2 VALU ops
__device__ __forceinline__ float lrelu(float v) {
    return fmaxf(v, LRELU_NS * v);
}
// vector lrelu: add/mul/max all vectorizable to v_pk_* (dual-issue f32)
__device__ __forceinline__ floatx4 lrelu4(floatx4 a, floatx4 b) {
    floatx4 h = a + b;
    floatx4 hm = h * LRELU_NS;
#if __has_builtin(__builtin_elementwise_max)
    return __builtin_elementwise_max(h, hm);
#else
    floatx4 r;
    r[0] = fmaxf(h[0], hm[0]); r[1] = fmaxf(h[1], hm[1]);
    r[2] = fmaxf(h[2], hm[2]); r[3] = fmaxf(h[3], hm[3]);
    return r;
#endif
}
// dtype-adaptive element fetch (isF32 is block-uniform)
__device__ __forceinline__ u16 ldW(const void* p, int i, int isF32) {
    return isF32 ? f2bf(((const float*)p)[i]) : ((const u16*)p)[i];
}
__device__ __forceinline__ float ldF(const void* p, int i, int isF32) {
    return isF32 ? ((const float*)p)[i]
                 : bitsToF((unsigned int)((const u16*)p)[i]);
}

// ---------------------------------------------------------------------------
// Inlined dtype probe (verified R8/R12). Call unconditionally, all threads.
// ---------------------------------------------------------------------------
__device__ __forceinline__ int computeIsF32(const u16* y, int* cnt, int t) {
    if (t == 0) *cnt = 0;
    __syncthreads();
    if (t < 256) {
        u16 v = y[2 * t];
        int e = (v >> 7) & 0xFF;
        if (v == 0 || (e >= 96 && e < 160)) atomicAdd(cnt, 1);
    }
    __syncthreads();
    return (*cnt < 192) ? 1 : 0;
}

// ---------------------------------------------------------------------------
// Kernel 1: pack — UNCHANGED from R12 (verified).
// ---------------------------------------------------------------------------
__global__ __launch_bounds__(256) void pack_kernel(
    const void* __restrict__ yhat,
    const void* __restrict__ Ws1, const void* __restrict__ Wc1,
    const void* __restrict__ Wb1, const void* __restrict__ Ws2,
    const void* __restrict__ Wc2,
    const void* __restrict__ bs1, const void* __restrict__ bc1,
    const void* __restrict__ bb1, const void* __restrict__ bs2,
    const void* __restrict__ bc2, const void* __restrict__ bb2,
    u16* __restrict__ WallT, u16* __restrict__ W2T, float* __restrict__ biasF,
    u16* __restrict__ Xbf)
{
    __shared__ int fcnt;
    const int bid = blockIdx.x, t = threadIdx.x;
    const int isF32 = computeIsF32((const u16*)yhat, &fcnt, t);
    if (bid < 64) {
        __shared__ u16 tile[64][65];
        const int c0 = (bid & 15) * 64;
        const int k0 = (bid >> 4) * 64;
        const void* src; int coff; int roff = 0;
        if (c0 < 256)      { src = Ws1; coff = c0; }
        else if (c0 < 512) { src = Wc1; coff = c0 - 256; }
        else if (c0 < 768) { src = Wb1; coff = c0 - 512; }
        else               { src = Wb1; coff = c0 - 768; roff = 256; }
        const int cc = t & 63, kk0 = t >> 6;
        #pragma unroll
        for (int i = 0; i < 16; ++i) {
            int kk = kk0 + i * 4;
            tile[kk][cc] = ldW(src, (k0 + kk + roff) * 256 + coff + cc, isF32);
        }
        __syncthreads();
        const int kk2 = t & 63, cc0 = t >> 6;
        #pragma unroll
        for (int i = 0; i < 16; ++i) {
            int cc2 = cc0 + i * 4;
            WallT[(c0 + cc2) * 256 + (k0 + kk2)] = tile[kk2][cc2];
        }
    } else if (bid < 128) {
        int e2 = (bid - 64) * 256 + t;
        int c = e2 >> 8, k = e2 & 255;
        u16 v = 0;
        if (c < 40)                 v = ldW(Ws2, k * 40 + c, isF32);
        else if (c >= 48 && c < 53) v = ldW(Wc2, k * 5 + (c - 48), isF32);
        W2T[c * 256 + k] = v;
    } else if (bid < 132) {
        int idx = (bid - 128) * 256 + t;
        float v = 0.f;
        if (idx < 256)       v = ldF(bs1, idx, isF32);
        else if (idx < 512)  v = ldF(bc1, idx - 256, isF32);
        else if (idx < 768)  v = ldF(bb1, idx - 512, isF32);
        else if (idx < 808)  v = ldF(bs2, idx - 768, isF32);
        else if (idx < 813)  v = ldF(bc2, idx - 808, isF32);
        else if (idx >= 816 && idx < 821) v = ldF(bb2, idx - 816, isF32);
        biasF[idx] = v;
    } else {
        if (!isF32) return;
        const floatx4* __restrict__ xf = (const floatx4*)yhat;
        const int base4 = (bid - 132) * 4096;
        #pragma unroll
        for (int it = 0; it < 16; ++it) {
            int c4 = base4 + t + it * 256;
            floatx4 f = xf[c4];
            ushort4v u;
            u[0] = f2bf(f[0]); u[1] = f2bf(f[1]); u[2] = f2bf(f[2]); u[3] = f2bf(f[3]);
            *(ushort4v*)&Xbf[c4 * 4] = u;
        }
    }
}

// ---------------------------------------------------------------------------
// Kernel 2: symbols + charges — UNCHANGED from R12 (verified).
// ---------------------------------------------------------------------------
__global__ __launch_bounds__(256, 4) void heads_kernel(
    const void* __restrict__ Xv, const u16* __restrict__ Xbf,
    const u16* __restrict__ WallT,
    const u16* __restrict__ W2T, const float* __restrict__ biasF,
    void* __restrict__ outv)
{
    __shared__ u16 Hb[64 * SK];
    __shared__ int fcnt;
    const int t = threadIdx.x;
    const int bm0 = blockIdx.x * 64;
    const int head = blockIdx.y;
    const int isF32 = computeIsF32((const u16*)Xv, &fcnt, t);
    const u16* __restrict__ Xb = isF32 ? Xbf : (const u16*)Xv;

    const int w = t >> 6, l = t & 63;
    const int ml = l & 15, kq = l >> 4, r0 = kq * 4;

    bf16x8 a8[8];
    {
        const u16* __restrict__ ap = Xb + (bm0 + w * 16 + ml) * 256 + kq * 8;
        #pragma unroll
        for (int ks = 0; ks < 8; ++ks)
            a8[ks] = *(const bf16x8*)(ap + ks * 32);
    }

    for (int ct = 0; ct < 16; ++ct) {
        floatx4 acc = {};
        #pragma unroll
        for (int ks = 0; ks < 8; ++ks) {
            const int k0 = ks * 32 + kq * 8;
            bf16x8 bf = *(const bf16x8*)&WallT[(head * 256 + ct * 16 + ml) * 256 + k0];
            acc = __builtin_amdgcn_mfma_f32_16x16x32_bf16(a8[ks], bf, acc, 0, 0, 0);
        }
        const int col = ct * 16 + ml;
        const float bias = biasF[head * 256 + col];
        #pragma unroll
        for (int r = 0; r < 4; ++r)
            Hb[(w * 16 + r0 + r) * SK + col] = f2bf(lrelu(acc[r] + bias));
    }
    // no barrier: layer 2 reads only rows written by this wave

    const int nct = (head == 0) ? 3 : 1;
    const int c0  = (head == 0) ? 0 : 48;
    floatx4 acc2[3] = {};
    #pragma unroll
    for (int ks = 0; ks < 8; ++ks) {
        const int k0 = ks * 32 + kq * 8;
        bf16x8 a = *(const bf16x8*)&Hb[(w * 16 + ml) * SK + k0];
        #pragma unroll
        for (int j = 0; j < 3; ++j) {
            if (j < nct) {
                bf16x8 bf = *(const bf16x8*)&W2T[(c0 + j * 16 + ml) * 256 + k0];
                acc2[j] = __builtin_amdgcn_mfma_f32_16x16x32_bf16(a, bf, acc2[j], 0, 0, 0);
            }
        }
    }
    #pragma unroll
    for (int j = 0; j < 3; ++j) {
        if (j < nct) {
            const int col = j * 16 + ml;
            const int lim = (head == 0) ? 40 : 5;
            if (col < lim) {
                const float bias = biasF[(head == 0 ? 768 : 808) + col];
                #pragma unroll
                for (int r = 0; r < 4; ++r) {
                    const int row = bm0 + w * 16 + r0 + r;
                    const int o = (head == 0) ? row * 40 + col
                                              : 409600 + row * 5 + col;
                    const float v = acc2[j][r] + bias;
                    if (isF32) ((float*)outv)[o] = v;
                    else ((__hip_bfloat16*)outv)[o] = __float2bfloat16(v);
                }
            }
        }
    }
}

// ---------------------------------------------------------------------------
// Kernel 3: bonds — R14 shell; ONE delta: pair-phase assembly math vectorized
// (floatx4 add/mul/elementwise_max -> v_pk_add/mul/max_f32 dual-issue).
// LDS: P1F 51456 + P2F 51456 + WsB 8448 + fb 16000 = 127360 B.
// ---------------------------------------------------------------------------
__global__ __launch_bounds__(512, 2) void bonds_kernel(
    const void* __restrict__ Xv, const u16* __restrict__ Xbf,
    const u16* __restrict__ WallT,
    const void* __restrict__ Wb2, const float* __restrict__ biasF,
    void* __restrict__ outv)
{
    __shared__ float P1F[48 * PF];
    __shared__ float P2F[48 * PF];
    __shared__ u16 WsB[16 * 264];
    __shared__ u16 fb[8000];
    __shared__ int fcnt;
    const int t = threadIdx.x, b = blockIdx.x;
    const int isF32 = computeIsF32((const u16*)Xv, &fcnt, t);
    const u16* __restrict__ Xb = isF32 ? Xbf : (const u16*)Xv;

    // Wb2[256][5] -> WsB[c][k] bf16, c<16 (rows 5..15 zero)
    #pragma unroll
    for (int it = 0; it < 8; ++it) {
        int e2 = t + it * 512;                 // < 4096
        int c = e2 >> 8, k = e2 & 255;
        WsB[c * 264 + k] = (c < 5) ? ldW(Wb2, k * 5 + c, isF32) : (u16)0;
    }

    const int w = t >> 6, l = t & 63;          // w in [0,8)
    const int ml = l & 15, kq = l >> 4, r0 = kq * 4;

    // ---- layer 1: P = X @ Wb1 (+bb1 on P1 half); store fp32 ----
    const u16* __restrict__ xrow[3];
    #pragma unroll
    for (int mt = 0; mt < 3; ++mt) {
        int rr = mt * 16 + ml; if (rr > 39) rr = 39;
        xrow[mt] = Xb + (b * 40 + rr) * 256 + kq * 8;
    }
    for (int n = 0; n < 4; ++n) {
        const int gc = (w + 8 * n) * 16 + ml;  // [0,512)
        floatx4 acc[3] = {};
        #pragma unroll
        for (int ks = 0; ks < 8; ++ks) {
            const int k0 = ks * 32;
            bf16x8 bf = *(const bf16x8*)&WallT[(512 + gc) * 256 + kq * 8 + k0];
            #pragma unroll
            for (int i = 0; i < 3; ++i) {
                bf16x8 a = *(const bf16x8*)(xrow[i] + k0);
                acc[i] = __builtin_amdgcn_mfma_f32_16x16x32_bf16(a, bf, acc[i], 0, 0, 0);
            }
        }
        float* dst = (gc < 256) ? P1F : P2F;
        const int col = gc & 255;
        const float bias = (gc < 256) ? biasF[512 + gc] : 0.f;   // bb1 on P1
        #pragma unroll
        for (int i = 0; i < 3; ++i)
            #pragma unroll
            for (int r = 0; r < 4; ++r)
                dst[(i * 16 + r0 + r) * PF + col] = acc[i][r] + bias;
    }
    __syncthreads();   // P1F/P2F + WsB visible to all waves

    // ---- pair phase: wave w owns i in {w, w+8, w+16, w+24, w+32}; process
    // pairs (ia, ia+8) for g=0,1 and singleton ia=w+32 for g=2 ----
    bf16x8 wf[8];
    #pragma unroll
    for (int ks = 0; ks < 8; ++ks)
        wf[ks] = *(const bf16x8*)&WsB[ml * 264 + ks * 32 + kq * 8];

    #pragma unroll
    for (int g = 0; g < 3; ++g) {
        const int ia = w + 16 * g;             // < 40 always (w<8)
        const int ib = ia + 8;                 // invalid when g==2
        const bool two = (g < 2);

        floatx4 paA[16], paB[16];
        #pragma unroll
        for (int ks = 0; ks < 8; ++ks) {
            const int k0 = ks * 32 + kq * 8;
            paA[2 * ks]     = *(const floatx4*)&P1F[ia * PF + k0];
            paA[2 * ks + 1] = *(const floatx4*)&P1F[ia * PF + k0 + 4];
            if (two) {
                paB[2 * ks]     = *(const floatx4*)&P1F[ib * PF + k0];
                paB[2 * ks + 1] = *(const floatx4*)&P1F[ib * PF + k0 + 4];
            }
        }
        for (int jt = 0; jt < 3; ++jt) {
            floatx4 accA = {}, accB = {};
            #pragma unroll
            for (int ks = 0; ks < 8; ++ks) {
                const int k0 = ks * 32 + kq * 8;
                floatx4 pb0 = *(const floatx4*)&P2F[(jt * 16 + ml) * PF + k0];
                floatx4 pb1 = *(const floatx4*)&P2F[(jt * 16 + ml) * PF + k0 + 4];
                int4v aiA;
                {
                    floatx4 h0 = lrelu4(paA[2 * ks],     pb0);  // pk_add/mul/max
                    floatx4 h1 = lrelu4(paA[2 * ks + 1], pb1);
                    aiA[0] = (int)((unsigned int)f2bf(h0[0]) | ((unsigned int)f2bf(h0[1]) << 16));
                    aiA[1] = (int)((unsigned int)f2bf(h0[2]) | ((unsigned int)f2bf(h0[3]) << 16));
                    aiA[2] = (int)((unsigned int)f2bf(h1[0]) | ((unsigned int)f2bf(h1[1]) << 16));
                    aiA[3] = (int)((unsigned int)f2bf(h1[2]) | ((unsigned int)f2bf(h1[3]) << 16));
                }
                accA = __builtin_amdgcn_mfma_f32_16x16x32_bf16(
                    __builtin_bit_cast(bf16x8, aiA), wf[ks], accA, 0, 0, 0);
                if (two) {
                    int4v aiB;
                    floatx4 h0 = lrelu4(paB[2 * ks],     pb0);
                    floatx4 h1 = lrelu4(paB[2 * ks + 1], pb1);
                    aiB[0] = (int)((unsigned int)f2bf(h0[0]) | ((unsigned int)f2bf(h0[1]) << 16));
                    aiB[1] = (int)((unsigned int)f2bf(h0[2]) | ((unsigned int)f2bf(h0[3]) << 16));
                    aiB[2] = (int)((unsigned int)f2bf(h1[0]) | ((unsigned int)f2bf(h1[1]) << 16));
                    aiB[3] = (int)((unsigned int)f2bf(h1[2]) | ((unsigned int)f2bf(h1[3]) << 16));
                    accB = __builtin_amdgcn_mfma_f32_16x16x32_bf16(
                        __builtin_bit_cast(bf16x8, aiB), wf[ks], accB, 0, 0, 0);
                }
            }
            if (ml < 5) {                      // D: row=kq*4+r (j'), col=ml
                #pragma unroll
                for (int r = 0; r < 4; ++r) {
                    const int j = jt * 16 + r0 + r;
                    if (j < 40) {
                        fb[(ia * 40 + j) * 5 + ml] = f2bf(accA[r]);
                        if (two) fb[(ib * 40 + j) * 5 + ml] = f2bf(accB[r]);
                    }
                }
            }
        }
    }
    __syncthreads();

    // ---- phase 2: symmetrize + 2*bb2 + store ----
    const int base = 460800 + b * 8000;
    for (int e = t; e < 8000; e += 512) {
        int pr = e / 5, c = e - pr * 5;
        int i = pr / 40, j = pr - (pr / 40) * 40;
        float v = bitsToF((unsigned int)fb[e])
                + bitsToF((unsigned int)fb[(j * 40 + i) * 5 + c])
                + 2.f * biasF[816 + c];
        if (isF32) ((float*)outv)[base + e] = v;
        else ((__hip_bfloat16*)outv)[base + e] = __float2bfloat16(v);
    }
}

// ---------------------------------------------------------------------------
extern "C" void kernel_launch(void* const* d_in, const int* in_sizes, int n_in,
                              void* d_out, int out_size, void* d_ws, size_t ws_size,
                              hipStream_t stream)
{
    const void* yhat = d_in[0];
    const void* Ws1  = d_in[1];
    const void* bs1  = d_in[2];
    const void* Ws2  = d_in[3];
    const void* bs2  = d_in[4];
    const void* Wc1  = d_in[5];
    const void* bc1  = d_in[6];
    const void* Wc2  = d_in[7];
    const void* bc2  = d_in[8];
    const void* Wb1  = d_in[9];
    const void* bb1  = d_in[10];
    const void* Wb2  = d_in[11];
    const void* bb2  = d_in[12];

    // workspace layout (5,808,128 bytes used)
    char* wsb = (char*)d_ws;
    float* biasF = (float*)(wsb + 4096);     // 1024 floats
    u16*   W2T   = (u16*)(wsb + 8192);       // 64*256 bf16  = 32768 B
    u16*   WallT = (u16*)(wsb + 40960);      // 1024*256 bf16 = 524288 B
    u16*   Xbf   = (u16*)(wsb + 565248);     // 10240*256 bf16 = 5242880 B

    pack_kernel<<<292, 256, 0, stream>>>(yhat, Ws1, Wc1, Wb1, Ws2, Wc2,
                                         bs1, bc1, bb1, bs2, bc2, bb2,
                                         WallT, W2T, biasF, Xbf);
    heads_kernel<<<dim3(160, 2), 256, 0, stream>>>(yhat, Xbf, WallT, W2T, biasF, d_out);
    bonds_kernel<<<256, 512, 0, stream>>>(yhat, Xbf, WallT, Wb2, biasF, d_out);
}